// Round 3
// baseline (1499.929 us; speedup 1.0000x reference)
//
#include <hip/hip_runtime.h>
#include <stdint.h>
#include <stddef.h>

typedef __bf16 bf16_t;
typedef __bf16 bf16x4 __attribute__((ext_vector_type(4)));
typedef __bf16 bf16x8 __attribute__((ext_vector_type(8)));
typedef float  f32x4  __attribute__((ext_vector_type(4)));

#define H_   12
#define N_   49
#define C_   384
#define D_   32
#define NW_  64
#define C3_  1152

// ---- LDS layout (bytes) ----
// region 0: xs (49 x 392 bf16) — current window input; refilled mid-P3 for next
// region 1: qa (49 x 392 bf16) — q [tok][dim], later ao
// region 2: ka (49 x 392 bf16) — k [tok][dim]; P3-core: per-wave P buffers
// region 3: vt (384 x 56 bf16, [dim][tok]) + 32B read guard
#define XS_STRIDE 392
#define Q_OFF     38416
#define K_OFF     76832
#define VT_OFF    115248
#define VT_STRIDE 56
#define P_STRIDE  72            // elems; per-wave P: 16 rows x 144B = 2304 B
#define SMEM_BYTES 158288       // 115248 + 384*112 + 32 guard

#define WQKV_ELEMS  (C3_ * C_)   // 442368
#define WPROJ_ELEMS (C_ * C_)    // 147456

#define NBLK 256
#define NITER 8                  // 2048 windows / 256 blocks

// ---------------------------------------------------------------------------
// prep_w: coalesced frag-order transpose of both weight matrices.
// ---------------------------------------------------------------------------
__global__ void prep_w(const float* __restrict__ qkv_w,
                       const float* __restrict__ proj_w,
                       bf16_t* __restrict__ wqkvT,
                       bf16_t* __restrict__ wprojT)
{
    __shared__ bf16_t tile[32][72];
    int bid = blockIdx.x;
    const float* src; bf16_t* dst; int NC, ks, g;
    if (bid < 216) { src = qkv_w;  dst = wqkvT;  NC = C3_; ks = bid % 12; g = bid / 12; }
    else { bid -= 216; src = proj_w; dst = wprojT; NC = C_;  ks = bid % 12; g = bid / 12; }
    const int n0 = g * 64;
    const int t = threadIdx.x;
    const int r0 = t >> 6, cc = t & 63;
    #pragma unroll
    for (int p = 0; p < 8; ++p) {
        int row = p * 4 + r0;
        tile[row][cc] = (bf16_t)src[(ks * 32 + row) * NC + n0 + cc];
    }
    __syncthreads();
    const int lane = t & 63, ctl = t >> 6;
    const int q4 = lane >> 4, l15 = lane & 15;
    bf16x8 v;
    #pragma unroll
    for (int j = 0; j < 8; ++j) v[j] = tile[q4 * 8 + j][ctl * 16 + l15];
    *(bf16x8*)(dst + ((size_t)((g * 4 + ctl) * 12 + ks) * 64 + lane) * 8) = v;
}

// ---------------------------------------------------------------------------
// prep_bias: T[w][h][m][n] = (rpb[h][m][n] + mask[w][m][n]) * log2(e), bf16.
// ---------------------------------------------------------------------------
__global__ void prep_bias(const float* __restrict__ mask,
                          const float* __restrict__ rpb,
                          bf16_t* __restrict__ T)
{
    const int w = blockIdx.x / H_, h = blockIdx.x % H_;
    bf16_t* out = T + (size_t)(w * H_ + h) * (N_ * 64);
    for (int idx = threadIdx.x; idx < N_ * 64; idx += 256) {
        int m = idx >> 6, n = idx & 63;
        float v = 0.f;
        if (n < N_)
            v = (rpb[(h * N_ + m) * N_ + n] + mask[((size_t)w * N_ + m) * N_ + n])
                * 1.4426950408889634f;
        out[idx] = (bf16_t)v;
    }
}

// ---------------------------------------------------------------------------
// Persistent fused kernel: 256 blocks (1/CU), each loops over 8 windows
// (w = b + 256*it). Software pipeline per iteration:
//   B0 | P2 qkv-GEMM | B1 | prefetch x[it+1]->regs + hoist qf/kf/vf | B2 |
//   P3 attn (P in ka region, ao staged immediately) + regs->xs | B3 | P4 proj
// x HBM latency hides under P3; bias table slice is constant across the 8
// iterations ((b+256*it)&63 == b&63) so it stays L2-hot.
// ---------------------------------------------------------------------------
__global__ __launch_bounds__(768, 3)
void fused_window_attn(const float* __restrict__ x,
                       const float* __restrict__ qkv_b,
                       const float* __restrict__ proj_b,
                       const bf16_t* __restrict__ wqkvT,
                       const bf16_t* __restrict__ wprojT,
                       const bf16_t* __restrict__ btbl,
                       float* __restrict__ out)
{
    __shared__ __align__(16) unsigned char smem[SMEM_BYTES];
    bf16_t* xs = (bf16_t*)smem;                 // window input
    bf16_t* qa = (bf16_t*)(smem + Q_OFF);       // q [tok][dim], later ao
    bf16_t* ka = (bf16_t*)(smem + K_OFF);       // k [tok][dim]; P3: P buffers
    bf16_t* vt = (bf16_t*)(smem + VT_OFF);      // v^T [dim][tok]

    const int tid  = threadIdx.x;
    const int wave = tid >> 6;                  // 0..11
    const int lane = tid & 63;
    const int q4   = lane >> 4;
    const int l15  = lane & 15;
    const int b    = blockIdx.x;                // 0..255

    const f32x4 z4 = {0.f, 0.f, 0.f, 0.f};
    const float SC = 0.17677669529663687f * 1.4426950408889634f;
    // bias table slice: constant across all 8 iterations of this block
    const bf16_t* tb = btbl + (size_t)((b & (NW_ - 1)) * H_ + wave) * (N_ * 64);

    float4 xr[7];   // register prefetch buffer for next window's x

    // ---------------- prologue: vt pad zero (once) + load x[b] ------------
    {
        // vt token-cols 48..55 and the 32B tail guard must be exact zeros:
        // PV b128 fragments read them (x P==0). Phase-2 epilogue B never
        // writes cols >= 49, so one-time zeroing survives all iterations.
        for (int t = tid; t < 384 * 8; t += 768) {
            int r = t >> 3, c = t & 7;
            vt[r * VT_STRIDE + 48 + c] = (bf16_t)0.f;
        }
        if (tid < 16) vt[384 * VT_STRIDE + tid] = (bf16_t)0.f;

        const float4* xg4 = (const float4*)(x + (size_t)b * (N_ * C_));
        #pragma unroll
        for (int kk = 0; kk < 6; ++kk) xr[kk] = xg4[tid + 768 * kk];
        if (tid < 96) xr[6] = xg4[tid + 4608];
        #pragma unroll
        for (int kk = 0; kk < 6; ++kk) {
            int t = tid + 768 * kk;
            int r = t / 96, c4 = t % 96;
            bf16x4 o;
            o[0] = (bf16_t)xr[kk].x; o[1] = (bf16_t)xr[kk].y;
            o[2] = (bf16_t)xr[kk].z; o[3] = (bf16_t)xr[kk].w;
            *(bf16x4*)(xs + r * XS_STRIDE + c4 * 4) = o;
        }
        if (tid < 96) {
            bf16x4 o;
            o[0] = (bf16_t)xr[6].x; o[1] = (bf16_t)xr[6].y;
            o[2] = (bf16_t)xr[6].z; o[3] = (bf16_t)xr[6].w;
            *(bf16x4*)(xs + 48 * XS_STRIDE + tid * 4) = o;
        }
    }

    #pragma unroll 1
    for (int it = 0; it < NITER; ++it) {
        const int w = b + NBLK * it;
        __syncthreads();   // B0: xs ready; prev P4's qa reads done

        // ---------------- phase 2: qkv GEMM, 6 column-tiles per wave ------
        if (wave < 8) {
            const int tbase = wave * 6;
            f32x4 acc[6][4];
            #pragma unroll
            for (int jj = 0; jj < 6; ++jj)
                #pragma unroll
                for (int mi = 0; mi < 4; ++mi) acc[jj][mi] = z4;

            for (int ks = 0; ks < 12; ++ks) {
                bf16x8 xf[4];
                #pragma unroll
                for (int mi = 0; mi < 4; ++mi)
                    xf[mi] = *(const bf16x8*)(xs + (mi * 16 + l15) * XS_STRIDE + ks * 32 + q4 * 8);
                #pragma unroll
                for (int jj = 0; jj < 6; ++jj) {
                    bf16x8 wf = *(const bf16x8*)(wqkvT +
                        ((size_t)((tbase + jj) * 12 + ks) * 64 + lane) * 8);
                    #pragma unroll
                    for (int mi = 0; mi < 4; ++mi)
                        acc[jj][mi] = __builtin_amdgcn_mfma_f32_16x16x32_bf16(
                            wf, xf[mi], acc[jj][mi], 0, 0, 0);
                }
            }
            // epilogue A: (chan=ct*16+q4*4+r, tok=l15) -> q/k [tok][chan]
            #pragma unroll
            for (int jj = 0; jj < 6; ++jj) {
                const int ct = tbase + jj;
                const int c0 = ct * 16 + q4 * 4;
                float4 bv = *(const float4*)(qkv_b + c0);
                bf16_t* dst = (ct < 24) ? qa : ka;
                const int cc = c0 - (ct < 24 ? 0 : C_);
                #pragma unroll
                for (int mi = 0; mi < 4; ++mi) {
                    const int m = mi * 16 + l15;
                    if (m < N_) {
                        bf16x4 o;
                        o[0] = (bf16_t)(acc[jj][mi][0] + bv.x);
                        o[1] = (bf16_t)(acc[jj][mi][1] + bv.y);
                        o[2] = (bf16_t)(acc[jj][mi][2] + bv.z);
                        o[3] = (bf16_t)(acc[jj][mi][3] + bv.w);
                        *(bf16x4*)(dst + m * XS_STRIDE + cc) = o;
                    }
                }
            }
        } else {
            const int tbase = 48 + (wave - 8) * 6;
            f32x4 acc[6][4];
            #pragma unroll
            for (int jj = 0; jj < 6; ++jj)
                #pragma unroll
                for (int mi = 0; mi < 4; ++mi) acc[jj][mi] = z4;

            for (int ks = 0; ks < 12; ++ks) {
                bf16x8 xf[4];
                #pragma unroll
                for (int mi = 0; mi < 4; ++mi)
                    xf[mi] = *(const bf16x8*)(xs + (mi * 16 + l15) * XS_STRIDE + ks * 32 + q4 * 8);
                #pragma unroll
                for (int jj = 0; jj < 6; ++jj) {
                    bf16x8 wf = *(const bf16x8*)(wqkvT +
                        ((size_t)((tbase + jj) * 12 + ks) * 64 + lane) * 8);
                    #pragma unroll
                    for (int mi = 0; mi < 4; ++mi)
                        acc[jj][mi] = __builtin_amdgcn_mfma_f32_16x16x32_bf16(
                            xf[mi], wf, acc[jj][mi], 0, 0, 0);
                }
            }
            // epilogue B: (tok=q4*4+r+mi*16, chan=ct*16+l15) -> vT [dim][tok]
            #pragma unroll
            for (int jj = 0; jj < 6; ++jj) {
                const int ct = tbase + jj;       // 48..71
                const int c  = ct * 16 + l15;
                const int d  = c - 2 * C_;       // v dim 0..383
                const float bb = qkv_b[c];
                #pragma unroll
                for (int mi = 0; mi < 4; ++mi) {
                    const int t0 = mi * 16 + q4 * 4;
                    if (t0 + 3 < N_) {
                        bf16x4 o;
                        #pragma unroll
                        for (int r = 0; r < 4; ++r) o[r] = (bf16_t)(acc[jj][mi][r] + bb);
                        *(bf16x4*)(vt + d * VT_STRIDE + t0) = o;
                    } else {
                        #pragma unroll
                        for (int r = 0; r < 4; ++r)
                            if (t0 + r < N_)
                                vt[d * VT_STRIDE + t0 + r] = (bf16_t)(acc[jj][mi][r] + bb);
                    }
                }
            }
        }
        __syncthreads();   // B1: q/k/vt ready; xs now dead

        // ---- P3-pre: issue next-x prefetch; hoist per-head fragments -----
        if (it < NITER - 1) {
            const float4* nxg = (const float4*)(x + (size_t)(w + NBLK) * (N_ * C_));
            #pragma unroll
            for (int kk = 0; kk < 6; ++kk) xr[kk] = nxg[tid + 768 * kk];
            if (tid < 96) xr[6] = nxg[tid + 4608];
        }
        bf16x8 qf[4], kf[4], vf[2][2];
        #pragma unroll
        for (int mt = 0; mt < 4; ++mt)
            qf[mt] = *(const bf16x8*)(qa + (mt * 16 + l15) * XS_STRIDE + wave * D_ + q4 * 8);
        #pragma unroll
        for (int ni = 0; ni < 4; ++ni)
            kf[ni] = *(const bf16x8*)(ka + (ni * 16 + l15) * XS_STRIDE + wave * D_ + q4 * 8);
        #pragma unroll
        for (int ks2 = 0; ks2 < 2; ++ks2)
            #pragma unroll
            for (int dt = 0; dt < 2; ++dt)
                vf[ks2][dt] = *(const bf16x8*)(vt + (wave * D_ + dt * 16 + l15) * VT_STRIDE
                                                  + ks2 * 32 + q4 * 8);
        __syncthreads();   // B2: q/k/vt dead as LDS; ka becomes P, qa becomes ao

        // ---------------- P3-core: wave = head, 4 row-tiles ---------------
        {
            bf16_t* pb = ka + wave * (P_STRIDE * 16);   // per-wave 16x72 bf16

            #pragma unroll
            for (int mt = 0; mt < 4; ++mt) {
                // S^T[n][m]
                f32x4 sacc[4];
                #pragma unroll
                for (int ni = 0; ni < 4; ++ni)
                    sacc[ni] = __builtin_amdgcn_mfma_f32_16x16x32_bf16(
                        kf[ni], qf[mt], z4, 0, 0, 0);

                // bias + exp2 + row sum (lane's m = mt*16+l15)
                const int m  = mt * 16 + l15;
                const int mc = m < 48 ? m : 48;
                float den = 0.f;
                #pragma unroll
                for (int ni = 0; ni < 4; ++ni) {
                    bf16x4 bv = *(const bf16x4*)(tb + (size_t)mc * 64 + ni * 16 + q4 * 4);
                    #pragma unroll
                    for (int r = 0; r < 4; ++r) {
                        const int n = ni * 16 + q4 * 4 + r;
                        float s = 0.f;
                        if (n < N_)
                            s = __builtin_exp2f(sacc[ni][r] * SC + (float)bv[r]);
                        sacc[ni][r] = s;
                        den += s;
                    }
                }
                den += __shfl_xor(den, 16);
                den += __shfl_xor(den, 32);
                const float ri = __builtin_amdgcn_rcpf(den);

                // P write (exact zeros for n>=49; rows m>=49 skipped)
                if (m < N_) {
                    #pragma unroll
                    for (int ni = 0; ni < 4; ++ni) {
                        bf16x4 o;
                        #pragma unroll
                        for (int r = 0; r < 4; ++r) o[r] = (bf16_t)(sacc[ni][r] * ri);
                        *(bf16x4*)(pb + l15 * P_STRIDE + ni * 16 + q4 * 4) = o;
                    }
                }

                // out = P @ V ; stage ao immediately (qa dead after B2)
                f32x4 o0 = z4, o1 = z4;
                #pragma unroll
                for (int ks2 = 0; ks2 < 2; ++ks2) {
                    bf16x8 pf = *(const bf16x8*)(pb + l15 * P_STRIDE + ks2 * 32 + q4 * 8);
                    o0 = __builtin_amdgcn_mfma_f32_16x16x32_bf16(pf, vf[ks2][0], o0, 0, 0, 0);
                    o1 = __builtin_amdgcn_mfma_f32_16x16x32_bf16(pf, vf[ks2][1], o1, 0, 0, 0);
                }
                #pragma unroll
                for (int r = 0; r < 4; ++r) {
                    const int ms = mt * 16 + q4 * 4 + r;
                    if (ms < N_) {
                        qa[ms * XS_STRIDE + wave * D_ + l15]      = (bf16_t)o0[r];
                        qa[ms * XS_STRIDE + wave * D_ + 16 + l15] = (bf16_t)o1[r];
                    }
                }
            }
        }

        // ---- write prefetched x -> xs (xs dead since B1) -----------------
        if (it < NITER - 1) {
            #pragma unroll
            for (int kk = 0; kk < 6; ++kk) {
                int t = tid + 768 * kk;
                int r = t / 96, c4 = t % 96;
                bf16x4 o;
                o[0] = (bf16_t)xr[kk].x; o[1] = (bf16_t)xr[kk].y;
                o[2] = (bf16_t)xr[kk].z; o[3] = (bf16_t)xr[kk].w;
                *(bf16x4*)(xs + r * XS_STRIDE + c4 * 4) = o;
            }
            if (tid < 96) {
                bf16x4 o;
                o[0] = (bf16_t)xr[6].x; o[1] = (bf16_t)xr[6].y;
                o[2] = (bf16_t)xr[6].z; o[3] = (bf16_t)xr[6].w;
                *(bf16x4*)(xs + 48 * XS_STRIDE + tid * 4) = o;
            }
        }
        __syncthreads();   // B3: ao staged, P dead, xs[it+1] ready

        // ---------------- phase 4: out = ao @ Wproj + b, 2 tiles/wave -----
        {
            f32x4 pacc[2][4];
            #pragma unroll
            for (int jj = 0; jj < 2; ++jj)
                #pragma unroll
                for (int mi = 0; mi < 4; ++mi) pacc[jj][mi] = z4;

            for (int ks = 0; ks < 12; ++ks) {
                bf16x8 af[4];
                #pragma unroll
                for (int mi = 0; mi < 4; ++mi)
                    af[mi] = *(const bf16x8*)(qa + (mi * 16 + l15) * XS_STRIDE + ks * 32 + q4 * 8);
                #pragma unroll
                for (int jj = 0; jj < 2; ++jj) {
                    bf16x8 wf = *(const bf16x8*)(wprojT +
                        ((size_t)((wave * 2 + jj) * 12 + ks) * 64 + lane) * 8);
                    #pragma unroll
                    for (int mi = 0; mi < 4; ++mi)
                        pacc[jj][mi] = __builtin_amdgcn_mfma_f32_16x16x32_bf16(
                            af[mi], wf, pacc[jj][mi], 0, 0, 0);
                }
            }
            float* og = out + (size_t)w * (N_ * C_);
            #pragma unroll
            for (int jj = 0; jj < 2; ++jj) {
                const int n = (wave * 2 + jj) * 16 + l15;
                const float bias = proj_b[n];
                #pragma unroll
                for (int mi = 0; mi < 4; ++mi) {
                    #pragma unroll
                    for (int r = 0; r < 4; ++r) {
                        const int m = mi * 16 + q4 * 4 + r;
                        if (m < N_) og[m * C_ + n] = pacc[jj][mi][r] + bias;
                    }
                }
            }
        }
    }
}

// ---------------------------------------------------------------------------
extern "C" void kernel_launch(void* const* d_in, const int* in_sizes, int n_in,
                              void* d_out, int out_size, void* d_ws, size_t ws_size,
                              hipStream_t stream)
{
    const float* x      = (const float*)d_in[0];
    const float* mask   = (const float*)d_in[1];
    const float* qkv_w  = (const float*)d_in[2];
    const float* qkv_b  = (const float*)d_in[3];
    const float* proj_w = (const float*)d_in[4];
    const float* proj_b = (const float*)d_in[5];
    const float* rpb    = (const float*)d_in[6];
    float* out = (float*)d_out;

    bf16_t* wqkvT  = (bf16_t*)d_ws;
    bf16_t* wprojT = wqkvT + WQKV_ELEMS;
    bf16_t* btbl   = wprojT + WPROJ_ELEMS;   // 64*12*49*64 bf16 = 4.8 MB

    prep_w<<<288, 256, 0, stream>>>(qkv_w, proj_w, wqkvT, wprojT);
    prep_bias<<<NW_ * H_, 256, 0, stream>>>(mask, rpb, btbl);
    fused_window_attn<<<NBLK, 768, 0, stream>>>(x, qkv_b, proj_b,
                                                wqkvT, wprojT, btbl, out);
}

// Round 4
// 509.933 us; speedup vs baseline: 2.9414x; 2.9414x over previous
//
#include <hip/hip_runtime.h>
#include <stdint.h>
#include <stddef.h>

typedef __bf16 bf16_t;
typedef __bf16 bf16x4 __attribute__((ext_vector_type(4)));
typedef __bf16 bf16x8 __attribute__((ext_vector_type(8)));
typedef float  f32x4  __attribute__((ext_vector_type(4)));

#define H_   12
#define N_   49
#define C_   384
#define D_   32
#define NW_  64
#define C3_  1152

// ---- LDS layout (bytes) ----
// region 0: xs (phase1/2: 49 x 392 bf16) / per-wave P buffers (phase 3)
// region 1: qa (49 x 392 bf16) — q [tok][dim] in P3, ao in P4
// region 2: ka (49 x 392 bf16) — k [tok][dim]
// region 3: vt (384 x 56 bf16, [dim][tok]) + 32B read guard
#define XS_STRIDE 392
#define Q_OFF     38416
#define K_OFF     76832
#define VT_OFF    115248
#define VT_STRIDE 56
#define P_STRIDE  72            // elems; per-wave P: 16 rows x 144B = 2304 B
#define SMEM_BYTES 158288       // 115248 + 384*112 + 32 guard

#define WQKV_ELEMS  (C3_ * C_)   // 442368
#define WPROJ_ELEMS (C_ * C_)    // 147456

// ---------------------------------------------------------------------------
// prep_all: merged weight transpose + bias table build (one launch).
// blocks 0..287: frag-order transpose of qkv_w/proj_w.
// blocks 288..1055: btbl[w][h][m][n] = (rpb+mask)*log2e, n padded to 64.
// ---------------------------------------------------------------------------
__global__ void prep_all(const float* __restrict__ qkv_w,
                         const float* __restrict__ proj_w,
                         const float* __restrict__ mask,
                         const float* __restrict__ rpb,
                         bf16_t* __restrict__ wqkvT,
                         bf16_t* __restrict__ wprojT,
                         bf16_t* __restrict__ btbl)
{
    __shared__ bf16_t tile[32][72];
    int bid = blockIdx.x;
    const int t = threadIdx.x;
    if (bid < 288) {
        const float* src; bf16_t* dst; int NC, ks, g;
        if (bid < 216) { src = qkv_w;  dst = wqkvT;  NC = C3_; ks = bid % 12; g = bid / 12; }
        else { bid -= 216; src = proj_w; dst = wprojT; NC = C_;  ks = bid % 12; g = bid / 12; }
        const int n0 = g * 64;
        const int r0 = t >> 6, cc = t & 63;
        #pragma unroll
        for (int p = 0; p < 8; ++p) {
            int row = p * 4 + r0;
            tile[row][cc] = (bf16_t)src[(ks * 32 + row) * NC + n0 + cc];
        }
        __syncthreads();
        const int lane = t & 63, ctl = t >> 6;
        const int q4 = lane >> 4, l15 = lane & 15;
        bf16x8 v;
        #pragma unroll
        for (int j = 0; j < 8; ++j) v[j] = tile[q4 * 8 + j][ctl * 16 + l15];
        *(bf16x8*)(dst + ((size_t)((g * 4 + ctl) * 12 + ks) * 64 + lane) * 8) = v;
    } else {
        bid -= 288;
        const int w = bid / H_, h = bid % H_;
        bf16_t* out = btbl + (size_t)(w * H_ + h) * (N_ * 64);
        for (int idx = t; idx < N_ * 64; idx += 256) {
            int m = idx >> 6, n = idx & 63;
            float v = 0.f;
            if (n < N_)
                v = (rpb[(h * N_ + m) * N_ + n] + mask[((size_t)w * N_ + m) * N_ + n])
                    * 1.4426950408889634f;
            out[idx] = (bf16_t)v;
        }
    }
}

// ---------------------------------------------------------------------------
// Fused per-window kernel: one block per window b, 12 waves (768 threads).
//   phase 2: 72 column-tiles -> 6/wave (waves 0..7 A-type q/k, 8..11 B-type v)
//   phase 3: wave = head (12 heads), 4 query row-tiles each; ao staged inline
//            (wave-private qa columns; row tiles written are never re-read)
//   phase 4: 24 column-tiles -> 2/wave
// 3 barriers per block (was 4): P1 | s | P2 | s | P3+stage | s | P4.
// ---------------------------------------------------------------------------
__global__ __launch_bounds__(768, 3)
void fused_window_attn(const float* __restrict__ x,
                       const float* __restrict__ qkv_b,
                       const float* __restrict__ proj_b,
                       const bf16_t* __restrict__ wqkvT,
                       const bf16_t* __restrict__ wprojT,
                       const bf16_t* __restrict__ btbl,
                       float* __restrict__ out)
{
    __shared__ __align__(16) unsigned char smem[SMEM_BYTES];
    bf16_t* xs = (bf16_t*)smem;                 // phase 1/2; P buffers in P3
    bf16_t* qa = (bf16_t*)(smem + Q_OFF);       // q [tok][dim], later ao
    bf16_t* ka = (bf16_t*)(smem + K_OFF);       // k [tok][dim]
    bf16_t* vt = (bf16_t*)(smem + VT_OFF);      // v^T [dim][tok]

    const int tid  = threadIdx.x;
    const int wave = tid >> 6;                  // 0..11
    const int lane = tid & 63;
    const int q4   = lane >> 4;
    const int l15  = lane & 15;
    const int b    = blockIdx.x;

    const f32x4 z4 = {0.f, 0.f, 0.f, 0.f};

    // ---------------- phase 1: x[b] -> bf16 LDS; zero vt padding ----------
    {
        // Zero vt token-columns 48..55 of every row + the 32B tail guard.
        // Tokens 49..55 are never written by phase 2 but ARE read (x P==0)
        // by the PV b128 fragments: 0*NaN = NaN, so they must be real zeros.
        for (int t = tid; t < 384 * 8; t += 768) {
            int r = t >> 3, c = t & 7;
            vt[r * VT_STRIDE + 48 + c] = (bf16_t)0.f;
        }
        if (tid < 16) vt[384 * VT_STRIDE + tid] = (bf16_t)0.f;

        const float* xg = x + (size_t)b * (N_ * C_);
        for (int t = tid; t < (N_ * C_) / 4; t += 768) {
            float4 v = ((const float4*)xg)[t];
            int r = t / 96, c4 = t % 96;
            bf16x4 o;
            o[0] = (bf16_t)v.x; o[1] = (bf16_t)v.y;
            o[2] = (bf16_t)v.z; o[3] = (bf16_t)v.w;
            *(bf16x4*)(xs + r * XS_STRIDE + c4 * 4) = o;
        }
    }
    __syncthreads();

    // ---------------- phase 2: qkv GEMM, 6 column-tiles per wave ----------
    // waves 0..7:  A-type (swapped operands), q+k cols, ct = wave*6 .. +5
    // waves 8..11: B-type (normal), v cols, ct = 48 + (wave-8)*6 .. +5
    if (wave < 8) {
        const int tbase = wave * 6;
        f32x4 acc[6][4];
        #pragma unroll
        for (int jj = 0; jj < 6; ++jj)
            #pragma unroll
            for (int mi = 0; mi < 4; ++mi) acc[jj][mi] = z4;

        for (int ks = 0; ks < 12; ++ks) {
            bf16x8 xf[4];
            #pragma unroll
            for (int mi = 0; mi < 4; ++mi)
                xf[mi] = *(const bf16x8*)(xs + (mi * 16 + l15) * XS_STRIDE + ks * 32 + q4 * 8);
            #pragma unroll
            for (int jj = 0; jj < 6; ++jj) {
                bf16x8 wf = *(const bf16x8*)(wqkvT +
                    ((size_t)((tbase + jj) * 12 + ks) * 64 + lane) * 8);
                #pragma unroll
                for (int mi = 0; mi < 4; ++mi)
                    acc[jj][mi] = __builtin_amdgcn_mfma_f32_16x16x32_bf16(
                        wf, xf[mi], acc[jj][mi], 0, 0, 0);
            }
        }
        // epilogue A: (chan=ct*16+q4*4+r, tok=l15) -> q/k [tok][chan]
        #pragma unroll
        for (int jj = 0; jj < 6; ++jj) {
            const int ct = tbase + jj;
            const int c0 = ct * 16 + q4 * 4;
            float4 bv = *(const float4*)(qkv_b + c0);
            bf16_t* dst = (ct < 24) ? qa : ka;
            const int cc = c0 - (ct < 24 ? 0 : C_);
            #pragma unroll
            for (int mi = 0; mi < 4; ++mi) {
                const int m = mi * 16 + l15;
                if (m < N_) {
                    bf16x4 o;
                    o[0] = (bf16_t)(acc[jj][mi][0] + bv.x);
                    o[1] = (bf16_t)(acc[jj][mi][1] + bv.y);
                    o[2] = (bf16_t)(acc[jj][mi][2] + bv.z);
                    o[3] = (bf16_t)(acc[jj][mi][3] + bv.w);
                    *(bf16x4*)(dst + m * XS_STRIDE + cc) = o;
                }
            }
        }
    } else {
        const int tbase = 48 + (wave - 8) * 6;
        f32x4 acc[6][4];
        #pragma unroll
        for (int jj = 0; jj < 6; ++jj)
            #pragma unroll
            for (int mi = 0; mi < 4; ++mi) acc[jj][mi] = z4;

        for (int ks = 0; ks < 12; ++ks) {
            bf16x8 xf[4];
            #pragma unroll
            for (int mi = 0; mi < 4; ++mi)
                xf[mi] = *(const bf16x8*)(xs + (mi * 16 + l15) * XS_STRIDE + ks * 32 + q4 * 8);
            #pragma unroll
            for (int jj = 0; jj < 6; ++jj) {
                bf16x8 wf = *(const bf16x8*)(wqkvT +
                    ((size_t)((tbase + jj) * 12 + ks) * 64 + lane) * 8);
                #pragma unroll
                for (int mi = 0; mi < 4; ++mi)
                    acc[jj][mi] = __builtin_amdgcn_mfma_f32_16x16x32_bf16(
                        xf[mi], wf, acc[jj][mi], 0, 0, 0);
            }
        }
        // epilogue B: (tok=q4*4+r+mi*16, chan=ct*16+l15) -> vT [dim][tok]
        #pragma unroll
        for (int jj = 0; jj < 6; ++jj) {
            const int ct = tbase + jj;       // 48..71
            const int c  = ct * 16 + l15;
            const int d  = c - 2 * C_;       // v dim 0..383
            const float bb = qkv_b[c];
            #pragma unroll
            for (int mi = 0; mi < 4; ++mi) {
                const int t0 = mi * 16 + q4 * 4;
                if (t0 + 3 < N_) {
                    bf16x4 o;
                    #pragma unroll
                    for (int r = 0; r < 4; ++r) o[r] = (bf16_t)(acc[jj][mi][r] + bb);
                    *(bf16x4*)(vt + d * VT_STRIDE + t0) = o;
                } else {
                    #pragma unroll
                    for (int r = 0; r < 4; ++r)
                        if (t0 + r < N_)
                            vt[d * VT_STRIDE + t0 + r] = (bf16_t)(acc[jj][mi][r] + bb);
                }
            }
        }
    }
    __syncthreads();

    // ---------------- phase 3: attention, wave = head, 4 row-tiles --------
    // ao staged inline after each PV: wave h only touches qa columns
    // [h*32, h*32+32) (private), and the rows written for tile mt are
    // exactly mt*16..mt*16+15, never re-read by later qf[mt'>mt] loads.
    {
        bf16_t* pb = (bf16_t*)(smem + wave * 2304);   // 16 x 72 bf16 (xs dead)
        const bf16_t* tb = btbl + (size_t)((b & (NW_ - 1)) * H_ + wave) * (N_ * 64);
        const float SC = 0.17677669529663687f * 1.4426950408889634f;

        // K and V fragments for this head: loaded once, reused for all 4 mt
        bf16x8 kf[4];
        #pragma unroll
        for (int ni = 0; ni < 4; ++ni)
            kf[ni] = *(const bf16x8*)(ka + (ni * 16 + l15) * XS_STRIDE
                                         + wave * D_ + q4 * 8);
        bf16x8 vf[2][2];
        #pragma unroll
        for (int ks2 = 0; ks2 < 2; ++ks2)
            #pragma unroll
            for (int dt = 0; dt < 2; ++dt)
                vf[ks2][dt] = *(const bf16x8*)(vt + (wave * D_ + dt * 16 + l15) * VT_STRIDE
                                                  + ks2 * 32 + q4 * 8);

        #pragma unroll
        for (int mt = 0; mt < 4; ++mt) {
            bf16x8 qf = *(const bf16x8*)(qa + (mt * 16 + l15) * XS_STRIDE
                                            + wave * D_ + q4 * 8);
            // S^T[n][m]
            f32x4 sacc[4];
            #pragma unroll
            for (int ni = 0; ni < 4; ++ni)
                sacc[ni] = __builtin_amdgcn_mfma_f32_16x16x32_bf16(
                    kf[ni], qf, z4, 0, 0, 0);

            // bias + exp2 + row sum (lane's m = mt*16+l15)
            const int m  = mt * 16 + l15;
            const int mc = m < 48 ? m : 48;
            float den = 0.f;
            #pragma unroll
            for (int ni = 0; ni < 4; ++ni) {
                bf16x4 bv = *(const bf16x4*)(tb + (size_t)mc * 64 + ni * 16 + q4 * 4);
                #pragma unroll
                for (int r = 0; r < 4; ++r) {
                    const int n = ni * 16 + q4 * 4 + r;
                    float s = 0.f;
                    if (n < N_)
                        s = __builtin_exp2f(sacc[ni][r] * SC + (float)bv[r]);
                    sacc[ni][r] = s;
                    den += s;
                }
            }
            den += __shfl_xor(den, 16);
            den += __shfl_xor(den, 32);
            const float ri = __builtin_amdgcn_rcpf(den);

            // P write (exact zeros for n>=49; rows m>=49 skipped)
            if (m < N_) {
                #pragma unroll
                for (int ni = 0; ni < 4; ++ni) {
                    bf16x4 o;
                    #pragma unroll
                    for (int r = 0; r < 4; ++r) o[r] = (bf16_t)(sacc[ni][r] * ri);
                    *(bf16x4*)(pb + l15 * P_STRIDE + ni * 16 + q4 * 4) = o;
                }
            }

            // out = P @ V ; stage ao inline (rows mt*16..+15, own columns)
            f32x4 o0 = z4, o1 = z4;
            #pragma unroll
            for (int ks2 = 0; ks2 < 2; ++ks2) {
                bf16x8 pf = *(const bf16x8*)(pb + l15 * P_STRIDE + ks2 * 32 + q4 * 8);
                o0 = __builtin_amdgcn_mfma_f32_16x16x32_bf16(pf, vf[ks2][0], o0, 0, 0, 0);
                o1 = __builtin_amdgcn_mfma_f32_16x16x32_bf16(pf, vf[ks2][1], o1, 0, 0, 0);
            }
            #pragma unroll
            for (int r = 0; r < 4; ++r) {
                const int ms = mt * 16 + q4 * 4 + r;
                if (ms < N_) {
                    qa[ms * XS_STRIDE + wave * D_ + l15]      = (bf16_t)o0[r];
                    qa[ms * XS_STRIDE + wave * D_ + 16 + l15] = (bf16_t)o1[r];
                }
            }
        }
    }
    __syncthreads();   // ao complete (all columns) before P4 reads qa

    // ---------------- phase 4: out = ao @ Wproj + b, 2 tiles/wave ---------
    {
        f32x4 pacc[2][4];
        #pragma unroll
        for (int jj = 0; jj < 2; ++jj)
            #pragma unroll
            for (int mi = 0; mi < 4; ++mi) pacc[jj][mi] = z4;

        for (int ks = 0; ks < 12; ++ks) {
            bf16x8 af[4];
            #pragma unroll
            for (int mi = 0; mi < 4; ++mi)
                af[mi] = *(const bf16x8*)(qa + (mi * 16 + l15) * XS_STRIDE + ks * 32 + q4 * 8);
            #pragma unroll
            for (int jj = 0; jj < 2; ++jj) {
                bf16x8 wf = *(const bf16x8*)(wprojT +
                    ((size_t)((wave * 2 + jj) * 12 + ks) * 64 + lane) * 8);
                #pragma unroll
                for (int mi = 0; mi < 4; ++mi)
                    pacc[jj][mi] = __builtin_amdgcn_mfma_f32_16x16x32_bf16(
                        af[mi], wf, pacc[jj][mi], 0, 0, 0);
            }
        }
        float* og = out + (size_t)b * (N_ * C_);
        #pragma unroll
        for (int jj = 0; jj < 2; ++jj) {
            const int n = (wave * 2 + jj) * 16 + l15;
            const float bias = proj_b[n];
            #pragma unroll
            for (int mi = 0; mi < 4; ++mi) {
                #pragma unroll
                for (int r = 0; r < 4; ++r) {
                    const int m = mi * 16 + q4 * 4 + r;
                    if (m < N_) og[m * C_ + n] = pacc[jj][mi][r] + bias;
                }
            }
        }
    }
}

// ---------------------------------------------------------------------------
extern "C" void kernel_launch(void* const* d_in, const int* in_sizes, int n_in,
                              void* d_out, int out_size, void* d_ws, size_t ws_size,
                              hipStream_t stream)
{
    const float* x      = (const float*)d_in[0];
    const float* mask   = (const float*)d_in[1];
    const float* qkv_w  = (const float*)d_in[2];
    const float* qkv_b  = (const float*)d_in[3];
    const float* proj_w = (const float*)d_in[4];
    const float* proj_b = (const float*)d_in[5];
    const float* rpb    = (const float*)d_in[6];
    float* out = (float*)d_out;

    bf16_t* wqkvT  = (bf16_t*)d_ws;
    bf16_t* wprojT = wqkvT + WQKV_ELEMS;
    bf16_t* btbl   = wprojT + WPROJ_ELEMS;   // 64*12*49*64 bf16 = 4.8 MB

    prep_all<<<288 + NW_ * H_, 256, 0, stream>>>(qkv_w, proj_w, mask, rpb,
                                                 wqkvT, wprojT, btbl);
    fused_window_attn<<<2048, 768, 0, stream>>>(x, qkv_b, proj_b,
                                                wqkvT, wprojT, btbl, out);
}

// Round 5
// 474.521 us; speedup vs baseline: 3.1609x; 1.0746x over previous
//
#include <hip/hip_runtime.h>
#include <stdint.h>
#include <stddef.h>

typedef __bf16 bf16_t;
typedef __bf16 bf16x4 __attribute__((ext_vector_type(4)));
typedef __bf16 bf16x8 __attribute__((ext_vector_type(8)));
typedef float  f32x4  __attribute__((ext_vector_type(4)));

#define H_   12
#define N_   49
#define C_   384
#define D_   32
#define NW_  64
#define C3_  1152

// ---- LDS layout (bytes) ----
// region 0: xs (phase1/2: 49 x 392 bf16) / per-wave P buffers (phase 3)
// region 1: qa (49 x 392 bf16) — q [tok][dim] in P3, ao in P4
// region 2: ka (49 x 392 bf16) — k [tok][dim]
// region 3: vt (384 x 56 bf16, [dim][tok]) + 32B read guard
#define XS_STRIDE 392
#define Q_OFF     38416
#define K_OFF     76832
#define VT_OFF    115248
#define VT_STRIDE 56
#define P_STRIDE  72            // elems; per-wave P: 16 rows x 144B = 2304 B
#define SMEM_BYTES 158288       // 115248 + 384*112 + 32 guard

#define WQKV_ELEMS  (C3_ * C_)   // 442368
#define WPROJ_ELEMS (C_ * C_)    // 147456

// ---------------------------------------------------------------------------
// prep_all: merged weight transpose + bias table build (one launch).
// blocks 0..287: frag-order transpose of qkv_w/proj_w.
// blocks 288..1055: btbl[w][h][m][n] = (rpb+mask)*log2e, n padded to 64.
// ---------------------------------------------------------------------------
__global__ void prep_all(const float* __restrict__ qkv_w,
                         const float* __restrict__ proj_w,
                         const float* __restrict__ mask,
                         const float* __restrict__ rpb,
                         bf16_t* __restrict__ wqkvT,
                         bf16_t* __restrict__ wprojT,
                         bf16_t* __restrict__ btbl)
{
    __shared__ bf16_t tile[32][72];
    int bid = blockIdx.x;
    const int t = threadIdx.x;
    if (bid < 288) {
        const float* src; bf16_t* dst; int NC, ks, g;
        if (bid < 216) { src = qkv_w;  dst = wqkvT;  NC = C3_; ks = bid % 12; g = bid / 12; }
        else { bid -= 216; src = proj_w; dst = wprojT; NC = C_;  ks = bid % 12; g = bid / 12; }
        const int n0 = g * 64;
        const int r0 = t >> 6, cc = t & 63;
        #pragma unroll
        for (int p = 0; p < 8; ++p) {
            int row = p * 4 + r0;
            tile[row][cc] = (bf16_t)src[(ks * 32 + row) * NC + n0 + cc];
        }
        __syncthreads();
        const int lane = t & 63, ctl = t >> 6;
        const int q4 = lane >> 4, l15 = lane & 15;
        bf16x8 v;
        #pragma unroll
        for (int j = 0; j < 8; ++j) v[j] = tile[q4 * 8 + j][ctl * 16 + l15];
        *(bf16x8*)(dst + ((size_t)((g * 4 + ctl) * 12 + ks) * 64 + lane) * 8) = v;
    } else {
        bid -= 288;
        const int w = bid / H_, h = bid % H_;
        bf16_t* out = btbl + (size_t)(w * H_ + h) * (N_ * 64);
        for (int idx = t; idx < N_ * 64; idx += 256) {
            int m = idx >> 6, n = idx & 63;
            float v = 0.f;
            if (n < N_)
                v = (rpb[(h * N_ + m) * N_ + n] + mask[((size_t)w * N_ + m) * N_ + n])
                    * 1.4426950408889634f;
            out[idx] = (bf16_t)v;
        }
    }
}

// ---------------------------------------------------------------------------
// Fused per-window kernel: one block per window b, 12 waves (768 threads).
//   phase 2: 72 column-tiles -> 6/wave, split into TWO 3-tile passes so the
//            accumulator footprint halves (48 regs) and the freed registers
//            hold explicit 1-ahead prefetch of wf (L2) and xf (LDS).
//   phase 3: wave = head (12 heads), 4 query row-tiles; ao staged inline.
//   phase 4: 2 column-tiles/wave with the same 1-ahead prefetch pattern.
// All prefetch state lives strictly inside one barrier phase (no cross-
// barrier register liveness — round-3 spill lesson).
// ---------------------------------------------------------------------------
__global__ __launch_bounds__(768, 3)
void fused_window_attn(const float* __restrict__ x,
                       const float* __restrict__ qkv_b,
                       const float* __restrict__ proj_b,
                       const bf16_t* __restrict__ wqkvT,
                       const bf16_t* __restrict__ wprojT,
                       const bf16_t* __restrict__ btbl,
                       float* __restrict__ out)
{
    __shared__ __align__(16) unsigned char smem[SMEM_BYTES];
    bf16_t* xs = (bf16_t*)smem;                 // phase 1/2; P buffers in P3
    bf16_t* qa = (bf16_t*)(smem + Q_OFF);       // q [tok][dim], later ao
    bf16_t* ka = (bf16_t*)(smem + K_OFF);       // k [tok][dim]
    bf16_t* vt = (bf16_t*)(smem + VT_OFF);      // v^T [dim][tok]

    const int tid  = threadIdx.x;
    const int wave = tid >> 6;                  // 0..11
    const int lane = tid & 63;
    const int q4   = lane >> 4;
    const int l15  = lane & 15;
    const int b    = blockIdx.x;

    const f32x4 z4 = {0.f, 0.f, 0.f, 0.f};

    // ---------------- phase 1: x[b] -> bf16 LDS; zero vt padding ----------
    {
        // Zero vt token-columns 48..55 of every row + the 32B tail guard.
        // Tokens 49..55 are never written by phase 2 but ARE read (x P==0)
        // by the PV b128 fragments: 0*NaN = NaN, so they must be real zeros.
        for (int t = tid; t < 384 * 8; t += 768) {
            int r = t >> 3, c = t & 7;
            vt[r * VT_STRIDE + 48 + c] = (bf16_t)0.f;
        }
        if (tid < 16) vt[384 * VT_STRIDE + tid] = (bf16_t)0.f;

        const float* xg = x + (size_t)b * (N_ * C_);
        for (int t = tid; t < (N_ * C_) / 4; t += 768) {
            float4 v = ((const float4*)xg)[t];
            int r = t / 96, c4 = t % 96;
            bf16x4 o;
            o[0] = (bf16_t)v.x; o[1] = (bf16_t)v.y;
            o[2] = (bf16_t)v.z; o[3] = (bf16_t)v.w;
            *(bf16x4*)(xs + r * XS_STRIDE + c4 * 4) = o;
        }
    }
    __syncthreads();

    // ---------------- phase 2: qkv GEMM, 2 passes x 3 tiles per wave ------
    // waves 0..7:  A-type (swapped operands), q+k cols, ct = wave*6 .. +5
    // waves 8..11: B-type (normal), v cols, ct = 48 + (wave-8)*6 .. +5
    if (wave < 8) {
        #pragma unroll
        for (int p = 0; p < 2; ++p) {
            const int tb0 = wave * 6 + p * 3;
            f32x4 acc[3][4];
            #pragma unroll
            for (int jj = 0; jj < 3; ++jj)
                #pragma unroll
                for (int mi = 0; mi < 4; ++mi) acc[jj][mi] = z4;

            bf16x8 wfc[3], xfc[4];
            #pragma unroll
            for (int jj = 0; jj < 3; ++jj)
                wfc[jj] = *(const bf16x8*)(wqkvT +
                    ((size_t)((tb0 + jj) * 12 + 0) * 64 + lane) * 8);
            #pragma unroll
            for (int mi = 0; mi < 4; ++mi)
                xfc[mi] = *(const bf16x8*)(xs + (mi * 16 + l15) * XS_STRIDE + q4 * 8);

            #pragma unroll
            for (int ks = 0; ks < 12; ++ks) {
                bf16x8 wfn[3], xfn[4];
                if (ks < 11) {
                    #pragma unroll
                    for (int jj = 0; jj < 3; ++jj)
                        wfn[jj] = *(const bf16x8*)(wqkvT +
                            ((size_t)((tb0 + jj) * 12 + ks + 1) * 64 + lane) * 8);
                    #pragma unroll
                    for (int mi = 0; mi < 4; ++mi)
                        xfn[mi] = *(const bf16x8*)(xs + (mi * 16 + l15) * XS_STRIDE
                                                      + (ks + 1) * 32 + q4 * 8);
                }
                #pragma unroll
                for (int jj = 0; jj < 3; ++jj)
                    #pragma unroll
                    for (int mi = 0; mi < 4; ++mi)
                        acc[jj][mi] = __builtin_amdgcn_mfma_f32_16x16x32_bf16(
                            wfc[jj], xfc[mi], acc[jj][mi], 0, 0, 0);
                if (ks < 11) {
                    #pragma unroll
                    for (int jj = 0; jj < 3; ++jj) wfc[jj] = wfn[jj];
                    #pragma unroll
                    for (int mi = 0; mi < 4; ++mi) xfc[mi] = xfn[mi];
                }
            }
            // epilogue A: (chan=ct*16+q4*4+r, tok=l15) -> q/k [tok][chan]
            #pragma unroll
            for (int jj = 0; jj < 3; ++jj) {
                const int ct = tb0 + jj;
                const int c0 = ct * 16 + q4 * 4;
                float4 bv = *(const float4*)(qkv_b + c0);
                bf16_t* dst = (ct < 24) ? qa : ka;
                const int cc = c0 - (ct < 24 ? 0 : C_);
                #pragma unroll
                for (int mi = 0; mi < 4; ++mi) {
                    const int m = mi * 16 + l15;
                    if (m < N_) {
                        bf16x4 o;
                        o[0] = (bf16_t)(acc[jj][mi][0] + bv.x);
                        o[1] = (bf16_t)(acc[jj][mi][1] + bv.y);
                        o[2] = (bf16_t)(acc[jj][mi][2] + bv.z);
                        o[3] = (bf16_t)(acc[jj][mi][3] + bv.w);
                        *(bf16x4*)(dst + m * XS_STRIDE + cc) = o;
                    }
                }
            }
        }
    } else {
        #pragma unroll
        for (int p = 0; p < 2; ++p) {
            const int tb0 = 48 + (wave - 8) * 6 + p * 3;
            f32x4 acc[3][4];
            #pragma unroll
            for (int jj = 0; jj < 3; ++jj)
                #pragma unroll
                for (int mi = 0; mi < 4; ++mi) acc[jj][mi] = z4;

            bf16x8 wfc[3], xfc[4];
            #pragma unroll
            for (int jj = 0; jj < 3; ++jj)
                wfc[jj] = *(const bf16x8*)(wqkvT +
                    ((size_t)((tb0 + jj) * 12 + 0) * 64 + lane) * 8);
            #pragma unroll
            for (int mi = 0; mi < 4; ++mi)
                xfc[mi] = *(const bf16x8*)(xs + (mi * 16 + l15) * XS_STRIDE + q4 * 8);

            #pragma unroll
            for (int ks = 0; ks < 12; ++ks) {
                bf16x8 wfn[3], xfn[4];
                if (ks < 11) {
                    #pragma unroll
                    for (int jj = 0; jj < 3; ++jj)
                        wfn[jj] = *(const bf16x8*)(wqkvT +
                            ((size_t)((tb0 + jj) * 12 + ks + 1) * 64 + lane) * 8);
                    #pragma unroll
                    for (int mi = 0; mi < 4; ++mi)
                        xfn[mi] = *(const bf16x8*)(xs + (mi * 16 + l15) * XS_STRIDE
                                                      + (ks + 1) * 32 + q4 * 8);
                }
                #pragma unroll
                for (int jj = 0; jj < 3; ++jj)
                    #pragma unroll
                    for (int mi = 0; mi < 4; ++mi)
                        acc[jj][mi] = __builtin_amdgcn_mfma_f32_16x16x32_bf16(
                            xfc[mi], wfc[jj], acc[jj][mi], 0, 0, 0);
                if (ks < 11) {
                    #pragma unroll
                    for (int jj = 0; jj < 3; ++jj) wfc[jj] = wfn[jj];
                    #pragma unroll
                    for (int mi = 0; mi < 4; ++mi) xfc[mi] = xfn[mi];
                }
            }
            // epilogue B: (tok=q4*4+r+mi*16, chan=ct*16+l15) -> vT [dim][tok]
            #pragma unroll
            for (int jj = 0; jj < 3; ++jj) {
                const int ct = tb0 + jj;         // 48..71
                const int c  = ct * 16 + l15;
                const int d  = c - 2 * C_;       // v dim 0..383
                const float bb = qkv_b[c];
                #pragma unroll
                for (int mi = 0; mi < 4; ++mi) {
                    const int t0 = mi * 16 + q4 * 4;
                    if (t0 + 3 < N_) {
                        bf16x4 o;
                        #pragma unroll
                        for (int r = 0; r < 4; ++r) o[r] = (bf16_t)(acc[jj][mi][r] + bb);
                        *(bf16x4*)(vt + d * VT_STRIDE + t0) = o;
                    } else {
                        #pragma unroll
                        for (int r = 0; r < 4; ++r)
                            if (t0 + r < N_)
                                vt[d * VT_STRIDE + t0 + r] = (bf16_t)(acc[jj][mi][r] + bb);
                    }
                }
            }
        }
    }
    __syncthreads();

    // ---------------- phase 3: attention, wave = head, 4 row-tiles --------
    // ao staged inline after each PV: wave h only touches qa columns
    // [h*32, h*32+32) (private), and the rows written for tile mt are
    // exactly mt*16..mt*16+15, never re-read by later qf[mt'>mt] loads.
    {
        bf16_t* pb = (bf16_t*)(smem + wave * 2304);   // 16 x 72 bf16 (xs dead)
        const bf16_t* tb = btbl + (size_t)((b & (NW_ - 1)) * H_ + wave) * (N_ * 64);
        const float SC = 0.17677669529663687f * 1.4426950408889634f;

        // K and V fragments for this head: loaded once, reused for all 4 mt
        bf16x8 kf[4];
        #pragma unroll
        for (int ni = 0; ni < 4; ++ni)
            kf[ni] = *(const bf16x8*)(ka + (ni * 16 + l15) * XS_STRIDE
                                         + wave * D_ + q4 * 8);
        bf16x8 vf[2][2];
        #pragma unroll
        for (int ks2 = 0; ks2 < 2; ++ks2)
            #pragma unroll
            for (int dt = 0; dt < 2; ++dt)
                vf[ks2][dt] = *(const bf16x8*)(vt + (wave * D_ + dt * 16 + l15) * VT_STRIDE
                                                  + ks2 * 32 + q4 * 8);

        #pragma unroll
        for (int mt = 0; mt < 4; ++mt) {
            bf16x8 qf = *(const bf16x8*)(qa + (mt * 16 + l15) * XS_STRIDE
                                            + wave * D_ + q4 * 8);
            // S^T[n][m]
            f32x4 sacc[4];
            #pragma unroll
            for (int ni = 0; ni < 4; ++ni)
                sacc[ni] = __builtin_amdgcn_mfma_f32_16x16x32_bf16(
                    kf[ni], qf, z4, 0, 0, 0);

            // bias + exp2 + row sum (lane's m = mt*16+l15)
            const int m  = mt * 16 + l15;
            const int mc = m < 48 ? m : 48;
            float den = 0.f;
            #pragma unroll
            for (int ni = 0; ni < 4; ++ni) {
                bf16x4 bv = *(const bf16x4*)(tb + (size_t)mc * 64 + ni * 16 + q4 * 4);
                #pragma unroll
                for (int r = 0; r < 4; ++r) {
                    const int n = ni * 16 + q4 * 4 + r;
                    float s = 0.f;
                    if (n < N_)
                        s = __builtin_exp2f(sacc[ni][r] * SC + (float)bv[r]);
                    sacc[ni][r] = s;
                    den += s;
                }
            }
            den += __shfl_xor(den, 16);
            den += __shfl_xor(den, 32);
            const float ri = __builtin_amdgcn_rcpf(den);

            // P write (exact zeros for n>=49; rows m>=49 skipped)
            if (m < N_) {
                #pragma unroll
                for (int ni = 0; ni < 4; ++ni) {
                    bf16x4 o;
                    #pragma unroll
                    for (int r = 0; r < 4; ++r) o[r] = (bf16_t)(sacc[ni][r] * ri);
                    *(bf16x4*)(pb + l15 * P_STRIDE + ni * 16 + q4 * 4) = o;
                }
            }

            // out = P @ V ; stage ao inline (rows mt*16..+15, own columns)
            f32x4 o0 = z4, o1 = z4;
            #pragma unroll
            for (int ks2 = 0; ks2 < 2; ++ks2) {
                bf16x8 pf = *(const bf16x8*)(pb + l15 * P_STRIDE + ks2 * 32 + q4 * 8);
                o0 = __builtin_amdgcn_mfma_f32_16x16x32_bf16(pf, vf[ks2][0], o0, 0, 0, 0);
                o1 = __builtin_amdgcn_mfma_f32_16x16x32_bf16(pf, vf[ks2][1], o1, 0, 0, 0);
            }
            #pragma unroll
            for (int r = 0; r < 4; ++r) {
                const int ms = mt * 16 + q4 * 4 + r;
                if (ms < N_) {
                    qa[ms * XS_STRIDE + wave * D_ + l15]      = (bf16_t)o0[r];
                    qa[ms * XS_STRIDE + wave * D_ + 16 + l15] = (bf16_t)o1[r];
                }
            }
        }
    }
    __syncthreads();   // ao complete (all columns) before P4 reads qa

    // ---------------- phase 4: out = ao @ Wproj + b, 2 tiles/wave ---------
    {
        f32x4 pacc[2][4];
        #pragma unroll
        for (int jj = 0; jj < 2; ++jj)
            #pragma unroll
            for (int mi = 0; mi < 4; ++mi) pacc[jj][mi] = z4;

        bf16x8 wfc[2], afc[4];
        #pragma unroll
        for (int jj = 0; jj < 2; ++jj)
            wfc[jj] = *(const bf16x8*)(wprojT +
                ((size_t)((wave * 2 + jj) * 12 + 0) * 64 + lane) * 8);
        #pragma unroll
        for (int mi = 0; mi < 4; ++mi)
            afc[mi] = *(const bf16x8*)(qa + (mi * 16 + l15) * XS_STRIDE + q4 * 8);

        #pragma unroll
        for (int ks = 0; ks < 12; ++ks) {
            bf16x8 wfn[2], afn[4];
            if (ks < 11) {
                #pragma unroll
                for (int jj = 0; jj < 2; ++jj)
                    wfn[jj] = *(const bf16x8*)(wprojT +
                        ((size_t)((wave * 2 + jj) * 12 + ks + 1) * 64 + lane) * 8);
                #pragma unroll
                for (int mi = 0; mi < 4; ++mi)
                    afn[mi] = *(const bf16x8*)(qa + (mi * 16 + l15) * XS_STRIDE
                                                  + (ks + 1) * 32 + q4 * 8);
            }
            #pragma unroll
            for (int jj = 0; jj < 2; ++jj)
                #pragma unroll
                for (int mi = 0; mi < 4; ++mi)
                    pacc[jj][mi] = __builtin_amdgcn_mfma_f32_16x16x32_bf16(
                        afc[mi], wfc[jj], pacc[jj][mi], 0, 0, 0);
            if (ks < 11) {
                #pragma unroll
                for (int jj = 0; jj < 2; ++jj) wfc[jj] = wfn[jj];
                #pragma unroll
                for (int mi = 0; mi < 4; ++mi) afc[mi] = afn[mi];
            }
        }
        float* og = out + (size_t)b * (N_ * C_);
        #pragma unroll
        for (int jj = 0; jj < 2; ++jj) {
            const int n = (wave * 2 + jj) * 16 + l15;
            const float bias = proj_b[n];
            #pragma unroll
            for (int mi = 0; mi < 4; ++mi) {
                #pragma unroll
                for (int r = 0; r < 4; ++r) {
                    const int m = mi * 16 + q4 * 4 + r;
                    if (m < N_) og[m * C_ + n] = pacc[jj][mi][r] + bias;
                }
            }
        }
    }
}

// ---------------------------------------------------------------------------
extern "C" void kernel_launch(void* const* d_in, const int* in_sizes, int n_in,
                              void* d_out, int out_size, void* d_ws, size_t ws_size,
                              hipStream_t stream)
{
    const float* x      = (const float*)d_in[0];
    const float* mask   = (const float*)d_in[1];
    const float* qkv_w  = (const float*)d_in[2];
    const float* qkv_b  = (const float*)d_in[3];
    const float* proj_w = (const float*)d_in[4];
    const float* proj_b = (const float*)d_in[5];
    const float* rpb    = (const float*)d_in[6];
    float* out = (float*)d_out;

    bf16_t* wqkvT  = (bf16_t*)d_ws;
    bf16_t* wprojT = wqkvT + WQKV_ELEMS;
    bf16_t* btbl   = wprojT + WPROJ_ELEMS;   // 64*12*49*64 bf16 = 4.8 MB

    prep_all<<<288 + NW_ * H_, 256, 0, stream>>>(qkv_w, proj_w, mask, rpb,
                                                 wqkvT, wprojT, btbl);
    fused_window_attn<<<2048, 768, 0, stream>>>(x, qkv_b, proj_b,
                                                wqkvT, wprojT, btbl, out);
}